// Round 9
// baseline (598.875 us; speedup 1.0000x reference)
//
#include <hip/hip_runtime.h>
#include <cstdint>
#include <cstddef>

#define T_TOK 4096
#define DIM   1024
#define NEXP  8
#define HDIM  4096
#define NSLOT (2 * T_TOK)

#define BM 128
#define BN1 128   // gemm1 g-cols per block (single interleaved B)
#define BN2 256   // gemm2 out-cols per block
#define BK 32

typedef __attribute__((ext_vector_type(8))) short s16x8;
typedef __attribute__((ext_vector_type(4))) float f32x4;

__device__ __forceinline__ unsigned short f2bf(float f) {
    union { float f; unsigned u; } v; v.f = f;
    unsigned u = v.u;
    unsigned r = (u + 0x7FFFu + ((u >> 16) & 1u)) >> 16;  // RNE
    return (unsigned short)r;
}

// element offset into a [row][32] bf16 tile, 16B-chunk XOR swizzle:
// slot c of row holds global chunk c ^ ((row>>1)&3)
__device__ __forceinline__ int lds_off(int row, int kchunk) {
    return row * 32 + ((kchunk ^ ((row >> 1) & 3)) << 3);
}

// async global->LDS, 16B per lane; LDS dest wave-uniform base + lane*16.
__device__ __forceinline__ void gload16(const void* g, void* l) {
    __builtin_amdgcn_global_load_lds(
        (const __attribute__((address_space(1))) unsigned int*)g,
        (__attribute__((address_space(3))) unsigned int*)l, 16, 0, 0);
}

// ------- gating: fp32 logits, top-2 + write token-ordered bf16 xg ----------
__global__ __launch_bounds__(256) void gate_kernel(
    const float* __restrict__ x, const float* __restrict__ wg,
    int* __restrict__ tok_e, float* __restrict__ tok_w, int* __restrict__ counts,
    unsigned short* __restrict__ xg)
{
    int t = blockIdx.x * 4 + (threadIdx.x >> 6);
    int lane = threadIdx.x & 63;
    float acc[NEXP];
#pragma unroll
    for (int e = 0; e < NEXP; ++e) acc[e] = 0.f;
    const float* xrow = x + (size_t)t * DIM;
    unsigned short* xgrow = xg + (size_t)t * DIM;
    for (int d = lane; d < DIM; d += 64) {
        float xv = xrow[d];
        xgrow[d] = f2bf(xv);
        const float4* wr = (const float4*)(wg + (size_t)d * NEXP);
        float4 w0 = wr[0], w1v = wr[1];
        acc[0] += xv * w0.x;  acc[1] += xv * w0.y;
        acc[2] += xv * w0.z;  acc[3] += xv * w0.w;
        acc[4] += xv * w1v.x; acc[5] += xv * w1v.y;
        acc[6] += xv * w1v.z; acc[7] += xv * w1v.w;
    }
#pragma unroll
    for (int e = 0; e < NEXP; ++e)
#pragma unroll
        for (int off = 32; off > 0; off >>= 1)
            acc[e] += __shfl_xor(acc[e], off);
    if (lane == 0) {
        int i0 = 0;
#pragma unroll
        for (int e = 1; e < NEXP; ++e) if (acc[e] > acc[i0]) i0 = e;
        int i1 = (i0 == 0) ? 1 : 0;
#pragma unroll
        for (int e = 0; e < NEXP; ++e) if (e != i0 && acc[e] > acc[i1]) i1 = e;
        float w0 = 1.f / (1.f + __expf(acc[i1] - acc[i0]));
        tok_e[2 * t] = i0;  tok_e[2 * t + 1] = i1;
        tok_w[2 * t] = w0;  tok_w[2 * t + 1] = 1.f - w0;
        atomicAdd(&counts[i0], 1);
        atomicAdd(&counts[i1], 1);
    }
}

__global__ void scan_kernel(const int* __restrict__ counts,
                            int* __restrict__ offsets, int* __restrict__ cursor)
{
    if (threadIdx.x == 0) {
        int s = 0;
        for (int e = 0; e < NEXP; ++e) { offsets[e] = s; s += counts[e]; cursor[e] = 0; }
        offsets[NEXP] = s;
    }
}

__global__ __launch_bounds__(256) void assign_kernel(
    const int* __restrict__ tok_e, const float* __restrict__ tok_w,
    const int* __restrict__ offsets, int* __restrict__ cursor,
    int* __restrict__ rows_tok, float* __restrict__ rows_gate)
{
    int t = blockIdx.x * 256 + threadIdx.x;
    if (t >= T_TOK) return;
#pragma unroll
    for (int j = 0; j < 2; ++j) {
        int e = tok_e[2 * t + j];
        int pos = offsets[e] + atomicAdd(&cursor[e], 1);
        rows_tok[pos] = t;
        rows_gate[pos] = tok_w[2 * t + j];
    }
}

// ------------- transpose+convert: src [E][R][C] f32 -> dst [E][C][R] bf16 ---
__device__ __forceinline__ void tconv_body(
    const float* __restrict__ src, unsigned short* __restrict__ dst,
    int R, int C, int e, int bx, int by, int t)
{
    __shared__ unsigned int t_lds[64 * 33];
    int c0 = bx * 64, r0 = by * 64;
    int lane = t & 63, w = t >> 6;
    const float* s = src + (size_t)e * R * C + (size_t)(r0 + w * 16) * C + c0 + lane;
#pragma unroll
    for (int j = 0; j < 8; ++j) {
        float v0 = s[(size_t)(2 * j) * C];
        float v1 = s[(size_t)(2 * j + 1) * C];
        unsigned int pk = (unsigned int)f2bf(v0) | ((unsigned int)f2bf(v1) << 16);
        t_lds[lane * 33 + (w * 8 + j)] = pk;
    }
    __syncthreads();
    unsigned short* dbase = dst + (size_t)e * C * R;
#pragma unroll
    for (int rep = 0; rep < 2; ++rep) {
        int idx = rep * 256 + t;
        int c = idx >> 3, chunk = idx & 7;
        uint4 o;
        o.x = t_lds[c * 33 + chunk * 4 + 0];
        o.y = t_lds[c * 33 + chunk * 4 + 1];
        o.z = t_lds[c * 33 + chunk * 4 + 2];
        o.w = t_lds[c * 33 + chunk * 4 + 3];
        *(uint4*)(dbase + (size_t)(c0 + c) * R + r0 + chunk * 8) = o;
    }
}

// interleaved w1/w3 transpose: w13t[E][2H][D], row 2j = w1 col j, 2j+1 = w3.
__global__ __launch_bounds__(256) void tconv13i_kernel(
    const float* __restrict__ w1, const float* __restrict__ w3,
    unsigned short* __restrict__ w13t)
{
    __shared__ unsigned int t_lds[64 * 33];
    int z = blockIdx.z;
    int parity = (z >= NEXP) ? 1 : 0;
    int e = parity ? z - NEXP : z;
    const float* src = parity ? w3 : w1;
    const int R = DIM, C = HDIM;
    int c0 = blockIdx.x * 64, r0 = blockIdx.y * 64;
    int t = threadIdx.x;
    int lane = t & 63, w = t >> 6;
    const float* s = src + (size_t)e * R * C + (size_t)(r0 + w * 16) * C + c0 + lane;
#pragma unroll
    for (int j = 0; j < 8; ++j) {
        float v0 = s[(size_t)(2 * j) * C];
        float v1 = s[(size_t)(2 * j + 1) * C];
        unsigned int pk = (unsigned int)f2bf(v0) | ((unsigned int)f2bf(v1) << 16);
        t_lds[lane * 33 + (w * 8 + j)] = pk;
    }
    __syncthreads();
    unsigned short* dbase = w13t + (size_t)e * 2 * C * R;
#pragma unroll
    for (int rep = 0; rep < 2; ++rep) {
        int idx = rep * 256 + t;
        int c = idx >> 3, chunk = idx & 7;
        uint4 o;
        o.x = t_lds[c * 33 + chunk * 4 + 0];
        o.y = t_lds[c * 33 + chunk * 4 + 1];
        o.z = t_lds[c * 33 + chunk * 4 + 2];
        o.w = t_lds[c * 33 + chunk * 4 + 3];
        *(uint4*)(dbase + (size_t)(2 * (c0 + c) + parity) * R + r0 + chunk * 8) = o;
    }
}

__global__ __launch_bounds__(256) void tconv_kernel(
    const float* __restrict__ src, unsigned short* __restrict__ dst, int R, int C)
{
    tconv_body(src, dst, R, C, blockIdx.z, blockIdx.x, blockIdx.y, threadIdx.x);
}

// ------- GEMM1: g = xg @ w13t^T (single-B, interleaved); h via lane-pair ---
// Light block: BM=128 x BN1=128 g-cols, 8 waves (2Mx4N), wave 64x32,
// acc[4][2]=32 regs, LDS 3bufs x 16KB = 48.5 KB -> 3 blocks/CU (24 waves).
// Round-8 counted-vmcnt 3-buffer schedule (2 loads/stage -> vmcnt(2)).
// Epilogue: g-col parity = lane bit0; g3 = shfl_xor(g1,1); even lanes write
// h = silu(g1)*g3. Numerics identical to dual-B version.
__global__ __launch_bounds__(512, 6) void gemm1_kernel(
    const unsigned short* __restrict__ xg,
    const unsigned short* __restrict__ w13t,
    const int* __restrict__ rows_tok, const int* __restrict__ offsets,
    unsigned short* __restrict__ h)
{
    int e = blockIdx.z;
    int offs = offsets[e];
    int cnt  = offsets[e + 1] - offs;
    int m0 = blockIdx.y * BM;
    if (m0 >= cnt) return;
    int n0 = blockIdx.x * BN1;   // over 2H g-cols

    __shared__ unsigned short lds3[3][2][BM * BK];  // [buf][A,B] 48 KB
    __shared__ int toks[BM];

    int tid = threadIdx.x;
    if (tid < BM) toks[tid] = rows_tok[offs + min(m0 + tid, cnt - 1)];
    __syncthreads();

    int lane = tid & 63;
    int wid = tid >> 6;
    int wr = wid >> 2, wc = wid & 3;   // 2M x 4N
    int lr = lane & 15, lg = lane >> 4;

    int srow = tid >> 2;
    int g = (tid & 3) ^ ((srow >> 1) & 3);
    const unsigned short* asrc = xg   + (size_t)toks[srow] * DIM + g * 8;
    const unsigned short* bsrc = w13t + ((size_t)e * 2 * HDIM + n0 + srow) * DIM + g * 8;
    int ldsbase = wid * 512;           // shorts; wave-uniform

    f32x4 acc[4][2] = {};

    const int NT = DIM / BK;           // 32 K-tiles

    auto stage_t = [&](int b, int t) {
        int k0 = t * BK;
        gload16(asrc + k0, &lds3[b][0][ldsbase]);
        gload16(bsrc + k0, &lds3[b][1][ldsbase]);
    };

    stage_t(0, 0);
    stage_t(1, 1);

    int cur = 0;
    for (int t = 0; t < NT; ++t) {
        if (t == NT - 1) asm volatile("s_waitcnt vmcnt(0)" ::: "memory");
        else             asm volatile("s_waitcnt vmcnt(2)" ::: "memory");
        __builtin_amdgcn_s_barrier();

        int nxt = cur + 2; if (nxt >= 3) nxt -= 3;
        if (t + 2 < NT) stage_t(nxt, t + 2);

        s16x8 a[4], bf[2];
#pragma unroll
        for (int m = 0; m < 4; ++m)
            a[m] = *(const s16x8*)&lds3[cur][0][lds_off(wr * 64 + m * 16 + lr, lg)];
#pragma unroll
        for (int n = 0; n < 2; ++n)
            bf[n] = *(const s16x8*)&lds3[cur][1][lds_off(wc * 32 + n * 16 + lr, lg)];

        __builtin_amdgcn_s_setprio(1);
#pragma unroll
        for (int n = 0; n < 2; ++n)
#pragma unroll
            for (int m = 0; m < 4; ++m)
                acc[m][n] = __builtin_amdgcn_mfma_f32_16x16x32_bf16(a[m], bf[n], acc[m][n], 0, 0, 0);
        __builtin_amdgcn_s_setprio(0);

        __builtin_amdgcn_s_barrier();
        cur = cur + 1; if (cur == 3) cur = 0;
    }

    // epilogue: pair (even,odd) g-cols -> h = silu(g1)*g3; even lanes store
#pragma unroll
    for (int m = 0; m < 4; ++m)
#pragma unroll
        for (int n = 0; n < 2; ++n)
#pragma unroll
            for (int r = 0; r < 4; ++r) {
                float g1 = acc[m][n][r];
                float g3 = __shfl_xor(g1, 1);
                int row_local = wr * 64 + m * 16 + lg * 4 + r;
                if (((lane & 1) == 0) && (m0 + row_local < cnt)) {
                    int gcol = n0 + wc * 32 + n * 16 + lr;   // even
                    int hcol = gcol >> 1;
                    float hv = (g1 / (1.f + __expf(-g1))) * g3;
                    h[(size_t)(offs + m0 + row_local) * HDIM + hcol] = f2bf(hv);
                }
            }
}

// -------- GEMM2: out[tok] += gate * (h @ w2); 128x256 block, 64x64 wave ----
// 3-buffer counted-vmcnt schedule (LDS 72 KB, 2 blocks/CU). Exactly 2
// atomic contributions per out element -> bitwise deterministic.
__global__ __launch_bounds__(512, 4) void gemm2_kernel(
    const unsigned short* __restrict__ h, const unsigned short* __restrict__ w2t,
    const int* __restrict__ rows_tok, const float* __restrict__ rows_gate,
    const int* __restrict__ offsets, float* __restrict__ out)
{
    int e = blockIdx.z;
    int offs = offsets[e];
    int cnt  = offsets[e + 1] - offs;
    int m0 = blockIdx.y * BM;
    if (m0 >= cnt) return;
    int n0 = blockIdx.x * BN2;   // over DIM

    __shared__ unsigned short ldsA[3][BM * BK];   // 24 KB
    __shared__ unsigned short ldsB[3][BN2 * BK];  // 48 KB
    __shared__ int   toks[BM];
    __shared__ float gts[BM];

    int tid = threadIdx.x;
    if (tid < BM) {
        int p = offs + min(m0 + tid, cnt - 1);
        toks[tid] = rows_tok[p];
        gts[tid]  = rows_gate[p];
    }
    __syncthreads();

    int lane = tid & 63;
    int wid = tid >> 6;
    int wr = wid >> 2, wc = wid & 3;   // 2M x 4N, wave tile 64x64
    int lr = lane & 15, lg = lane >> 4;

    int srow = tid >> 2;               // 0..127
    int g = (tid & 3) ^ ((srow >> 1) & 3);
    int arow = offs + min(m0 + srow, cnt - 1);
    const unsigned short* asrc  = h + (size_t)arow * HDIM + g * 8;
    const unsigned short* bsrc0 = w2t + ((size_t)e * DIM + n0 + srow) * HDIM + g * 8;
    const unsigned short* bsrc1 = w2t + ((size_t)e * DIM + n0 + 128 + srow) * HDIM + g * 8;
    int ldsbase = wid * 512;

    f32x4 acc[4][4] = {};

    const int NT = HDIM / BK;          // 128 K-tiles

    auto stage_t = [&](int b, int t) {
        int k0 = t * BK;
        gload16(asrc + k0,  &ldsA[b][ldsbase]);
        gload16(bsrc0 + k0, &ldsB[b][ldsbase]);
        gload16(bsrc1 + k0, &ldsB[b][4096 + ldsbase]);
    };

    stage_t(0, 0);
    stage_t(1, 1);

    int cur = 0;
    for (int t = 0; t < NT; ++t) {
        if (t == NT - 1) asm volatile("s_waitcnt vmcnt(0)" ::: "memory");
        else             asm volatile("s_waitcnt vmcnt(3)" ::: "memory");
        __builtin_amdgcn_s_barrier();

        int nxt = cur + 2; if (nxt >= 3) nxt -= 3;
        if (t + 2 < NT) stage_t(nxt, t + 2);

        s16x8 a[4], bf[4];
#pragma unroll
        for (int m = 0; m < 4; ++m)
            a[m] = *(const s16x8*)&ldsA[cur][lds_off(wr * 64 + m * 16 + lr, lg)];
#pragma unroll
        for (int n = 0; n < 4; ++n)
            bf[n] = *(const s16x8*)&ldsB[cur][lds_off(wc * 64 + n * 16 + lr, lg)];

        __builtin_amdgcn_s_setprio(1);
#pragma unroll
        for (int n = 0; n < 4; ++n)
#pragma unroll
            for (int m = 0; m < 4; ++m)
                acc[m][n] = __builtin_amdgcn_mfma_f32_16x16x32_bf16(a[m], bf[n], acc[m][n], 0, 0, 0);
        __builtin_amdgcn_s_setprio(0);

        __builtin_amdgcn_s_barrier();
        cur = cur + 1; if (cur == 3) cur = 0;
    }

#pragma unroll
    for (int m = 0; m < 4; ++m)
#pragma unroll
        for (int n = 0; n < 4; ++n)
#pragma unroll
            for (int r = 0; r < 4; ++r) {
                int row_local = wr * 64 + m * 16 + lg * 4 + r;
                if (m0 + row_local < cnt) {
                    int col = n0 + wc * 64 + n * 16 + lr;
                    float v = acc[m][n][r] * gts[row_local];
                    atomicAdd(&out[(size_t)toks[row_local] * DIM + col], v);
                }
            }
}

// ---------------------------------------------------------------------------
extern "C" void kernel_launch(void* const* d_in, const int* in_sizes, int n_in,
                              void* d_out, int out_size, void* d_ws, size_t ws_size,
                              hipStream_t stream)
{
    const float* x  = (const float*)d_in[0];
    const float* wg = (const float*)d_in[1];
    const float* w1 = (const float*)d_in[2];
    const float* w3 = (const float*)d_in[3];
    const float* w2 = (const float*)d_in[4];
    float* out = (float*)d_out;

    // Workspace ~200.3 MiB. Alias: w2t <- w13t (dead after gemm1).
    char* ws = (char*)d_ws;
    size_t off = 0;
    auto alloc = [&](size_t bytes) -> void* {
        void* p = ws + off;
        off = (off + bytes + 255) & ~(size_t)255;
        return p;
    };
    int*   rows_tok  = (int*)alloc((size_t)NSLOT * 4);
    float* rows_gate = (float*)alloc((size_t)NSLOT * 4);
    int*   tok_e     = (int*)alloc((size_t)NSLOT * 4);
    float* tok_w     = (float*)alloc((size_t)NSLOT * 4);
    int*   counts    = (int*)alloc(NEXP * 4);
    int*   offsets   = (int*)alloc((NEXP + 1) * 4);
    int*   cursor    = (int*)alloc(NEXP * 4);
    unsigned short* xg   = (unsigned short*)alloc((size_t)T_TOK * DIM * 2);           // 8 MiB
    unsigned short* w13t = (unsigned short*)alloc((size_t)NEXP * 2 * HDIM * DIM * 2); // 128 MiB
    unsigned short* hbuf = (unsigned short*)alloc((size_t)NSLOT * HDIM * 2);          // 64 MiB
    unsigned short* w2t  = w13t;   // alias: dead after gemm1

    hipMemsetAsync(counts, 0, NEXP * 4, stream);
    hipMemsetAsync(out, 0, (size_t)out_size * sizeof(float), stream);

    gate_kernel<<<T_TOK / 4, 256, 0, stream>>>(x, wg, tok_e, tok_w, counts, xg);
    scan_kernel<<<1, 64, 0, stream>>>(counts, offsets, cursor);
    assign_kernel<<<T_TOK / 256, 256, 0, stream>>>(tok_e, tok_w, offsets, cursor,
                                                   rows_tok, rows_gate);

    // w1,w3: [E][D][H] -> interleaved w13t[E][2H][D] in one dispatch
    tconv13i_kernel<<<dim3(HDIM / 64, DIM / 64, 2 * NEXP), 256, 0, stream>>>(
        w1, w3, w13t);

    gemm1_kernel<<<dim3(2 * HDIM / BN1, T_TOK / BM, NEXP), 512, 0, stream>>>(
        xg, w13t, rows_tok, offsets, hbuf);

    // w2: [E][H][D] -> [E][D][H]  (into w13t's region, now dead)
    tconv_kernel<<<dim3(DIM / 64, HDIM / 64, NEXP), 256, 0, stream>>>(w2, w2t, HDIM, DIM);

    gemm2_kernel<<<dim3(DIM / BN2, T_TOK / BM, NEXP), 512, 0, stream>>>(
        hbuf, w2t, rows_tok, rows_gate, offsets, out);
}

// Round 10
// 583.074 us; speedup vs baseline: 1.0271x; 1.0271x over previous
//
#include <hip/hip_runtime.h>
#include <cstdint>
#include <cstddef>

#define T_TOK 4096
#define DIM   1024
#define NEXP  8
#define HDIM  4096
#define NSLOT (2 * T_TOK)

#define BM 128
#define BN1 128   // gemm1 h-cols per block (dual-B)
#define BN2 128   // gemm2 out-cols per block (m97 shape)
#define BK 32

typedef __attribute__((ext_vector_type(8))) short s16x8;
typedef __attribute__((ext_vector_type(4))) float f32x4;

__device__ __forceinline__ unsigned short f2bf(float f) {
    union { float f; unsigned u; } v; v.f = f;
    unsigned u = v.u;
    unsigned r = (u + 0x7FFFu + ((u >> 16) & 1u)) >> 16;  // RNE
    return (unsigned short)r;
}

// element offset into a [row][32] bf16 tile, 16B-chunk XOR swizzle:
// slot c of row holds global chunk c ^ ((row>>1)&3)
__device__ __forceinline__ int lds_off(int row, int kchunk) {
    return row * 32 + ((kchunk ^ ((row >> 1) & 3)) << 3);
}

// async global->LDS, 16B per lane; LDS dest wave-uniform base + lane*16.
__device__ __forceinline__ void gload16(const void* g, void* l) {
    __builtin_amdgcn_global_load_lds(
        (const __attribute__((address_space(1))) unsigned int*)g,
        (__attribute__((address_space(3))) unsigned int*)l, 16, 0, 0);
}

// ------- gating: fp32 logits, top-2 + write token-ordered bf16 xg ----------
__global__ __launch_bounds__(256) void gate_kernel(
    const float* __restrict__ x, const float* __restrict__ wg,
    int* __restrict__ tok_e, float* __restrict__ tok_w, int* __restrict__ counts,
    unsigned short* __restrict__ xg)
{
    int t = blockIdx.x * 4 + (threadIdx.x >> 6);
    int lane = threadIdx.x & 63;
    float acc[NEXP];
#pragma unroll
    for (int e = 0; e < NEXP; ++e) acc[e] = 0.f;
    const float* xrow = x + (size_t)t * DIM;
    unsigned short* xgrow = xg + (size_t)t * DIM;
    for (int d = lane; d < DIM; d += 64) {
        float xv = xrow[d];
        xgrow[d] = f2bf(xv);
        const float4* wr = (const float4*)(wg + (size_t)d * NEXP);
        float4 w0 = wr[0], w1v = wr[1];
        acc[0] += xv * w0.x;  acc[1] += xv * w0.y;
        acc[2] += xv * w0.z;  acc[3] += xv * w0.w;
        acc[4] += xv * w1v.x; acc[5] += xv * w1v.y;
        acc[6] += xv * w1v.z; acc[7] += xv * w1v.w;
    }
#pragma unroll
    for (int e = 0; e < NEXP; ++e)
#pragma unroll
        for (int off = 32; off > 0; off >>= 1)
            acc[e] += __shfl_xor(acc[e], off);
    if (lane == 0) {
        int i0 = 0;
#pragma unroll
        for (int e = 1; e < NEXP; ++e) if (acc[e] > acc[i0]) i0 = e;
        int i1 = (i0 == 0) ? 1 : 0;
#pragma unroll
        for (int e = 0; e < NEXP; ++e) if (e != i0 && acc[e] > acc[i1]) i1 = e;
        float w0 = 1.f / (1.f + __expf(acc[i1] - acc[i0]));
        tok_e[2 * t] = i0;  tok_e[2 * t + 1] = i1;
        tok_w[2 * t] = w0;  tok_w[2 * t + 1] = 1.f - w0;
        atomicAdd(&counts[i0], 1);
        atomicAdd(&counts[i1], 1);
    }
}

__global__ void scan_kernel(const int* __restrict__ counts,
                            int* __restrict__ offsets, int* __restrict__ cursor)
{
    if (threadIdx.x == 0) {
        int s = 0;
        for (int e = 0; e < NEXP; ++e) { offsets[e] = s; s += counts[e]; cursor[e] = 0; }
        offsets[NEXP] = s;
    }
}

__global__ __launch_bounds__(256) void assign_kernel(
    const int* __restrict__ tok_e, const float* __restrict__ tok_w,
    const int* __restrict__ offsets, int* __restrict__ cursor,
    int* __restrict__ rows_tok, float* __restrict__ rows_gate)
{
    int t = blockIdx.x * 256 + threadIdx.x;
    if (t >= T_TOK) return;
#pragma unroll
    for (int j = 0; j < 2; ++j) {
        int e = tok_e[2 * t + j];
        int pos = offsets[e] + atomicAdd(&cursor[e], 1);
        rows_tok[pos] = t;
        rows_gate[pos] = tok_w[2 * t + j];
    }
}

// ------------- transpose+convert: src [E][R][C] f32 -> dst [E][C][R] bf16 ---
__device__ __forceinline__ void tconv_body(
    const float* __restrict__ src, unsigned short* __restrict__ dst,
    int R, int C, int e, int bx, int by, int t)
{
    __shared__ unsigned int t_lds[64 * 33];
    int c0 = bx * 64, r0 = by * 64;
    int lane = t & 63, w = t >> 6;
    const float* s = src + (size_t)e * R * C + (size_t)(r0 + w * 16) * C + c0 + lane;
#pragma unroll
    for (int j = 0; j < 8; ++j) {
        float v0 = s[(size_t)(2 * j) * C];
        float v1 = s[(size_t)(2 * j + 1) * C];
        unsigned int pk = (unsigned int)f2bf(v0) | ((unsigned int)f2bf(v1) << 16);
        t_lds[lane * 33 + (w * 8 + j)] = pk;
    }
    __syncthreads();
    unsigned short* dbase = dst + (size_t)e * C * R;
#pragma unroll
    for (int rep = 0; rep < 2; ++rep) {
        int idx = rep * 256 + t;
        int c = idx >> 3, chunk = idx & 7;
        uint4 o;
        o.x = t_lds[c * 33 + chunk * 4 + 0];
        o.y = t_lds[c * 33 + chunk * 4 + 1];
        o.z = t_lds[c * 33 + chunk * 4 + 2];
        o.w = t_lds[c * 33 + chunk * 4 + 3];
        *(uint4*)(dbase + (size_t)(c0 + c) * R + r0 + chunk * 8) = o;
    }
}

__global__ __launch_bounds__(256) void tconv13_kernel(
    const float* __restrict__ w1, const float* __restrict__ w3,
    unsigned short* __restrict__ w1t, unsigned short* __restrict__ w3t)
{
    int z = blockIdx.z;
    if (z < NEXP)
        tconv_body(w1, w1t, DIM, HDIM, z, blockIdx.x, blockIdx.y, threadIdx.x);
    else
        tconv_body(w3, w3t, DIM, HDIM, z - NEXP, blockIdx.x, blockIdx.y, threadIdx.x);
}

__global__ __launch_bounds__(256) void tconv_kernel(
    const float* __restrict__ src, unsigned short* __restrict__ dst, int R, int C)
{
    tconv_body(src, dst, R, C, blockIdx.z, blockIdx.x, blockIdx.y, threadIdx.x);
}

// ---------------- GEMM1: h = silu(xg@w1) * (xg@w3), grouped by expert ------
// Round-8 best-measured config: 512 thr / 8 waves (2Mx4N), dual-B wave tile
// 64x32 each, 3-buffer counted-vmcnt (3 loads/stage -> vmcnt(3)), LDS 72 KB,
// 2 blocks/CU. MFMA:ds = 16:8 = 2.0.
__global__ __launch_bounds__(512, 4) void gemm1_kernel(
    const unsigned short* __restrict__ xg,
    const unsigned short* __restrict__ w1t, const unsigned short* __restrict__ w3t,
    const int* __restrict__ rows_tok, const int* __restrict__ offsets,
    unsigned short* __restrict__ h)
{
    int e = blockIdx.z;
    int offs = offsets[e];
    int cnt  = offsets[e + 1] - offs;
    int m0 = blockIdx.y * BM;
    if (m0 >= cnt) return;
    int n0 = blockIdx.x * BN1;

    __shared__ unsigned short lds3[3][3][BM * BK];  // [buf][A,B1,B3] 72 KB
    __shared__ int toks[BM];

    int tid = threadIdx.x;
    if (tid < BM) toks[tid] = rows_tok[offs + min(m0 + tid, cnt - 1)];
    __syncthreads();

    int lane = tid & 63;
    int wid = tid >> 6;
    int wr = wid >> 2, wc = wid & 3;   // 2M x 4N
    int lr = lane & 15, lg = lane >> 4;

    int srow = tid >> 2;
    int g = (tid & 3) ^ ((srow >> 1) & 3);
    const unsigned short* asrc  = xg  + (size_t)toks[srow] * DIM + g * 8;
    const unsigned short* b1src = w1t + ((size_t)e * HDIM + n0 + srow) * DIM + g * 8;
    const unsigned short* b3src = w3t + ((size_t)e * HDIM + n0 + srow) * DIM + g * 8;
    int ldsbase = wid * 512;           // shorts; wave-uniform

    f32x4 acc1[4][2] = {};
    f32x4 acc3[4][2] = {};

    const int NT = DIM / BK;           // 32 K-tiles

    auto stage_t = [&](int b, int t) {
        int k0 = t * BK;
        gload16(asrc + k0,  &lds3[b][0][ldsbase]);
        gload16(b1src + k0, &lds3[b][1][ldsbase]);
        gload16(b3src + k0, &lds3[b][2][ldsbase]);
    };

    stage_t(0, 0);
    stage_t(1, 1);

    int cur = 0;
    for (int t = 0; t < NT; ++t) {
        if (t == NT - 1) asm volatile("s_waitcnt vmcnt(0)" ::: "memory");
        else             asm volatile("s_waitcnt vmcnt(3)" ::: "memory");
        __builtin_amdgcn_s_barrier();

        int nxt = cur + 2; if (nxt >= 3) nxt -= 3;
        if (t + 2 < NT) stage_t(nxt, t + 2);

        s16x8 a[4], b1f[2], b3f[2];
#pragma unroll
        for (int m = 0; m < 4; ++m)
            a[m] = *(const s16x8*)&lds3[cur][0][lds_off(wr * 64 + m * 16 + lr, lg)];
#pragma unroll
        for (int n = 0; n < 2; ++n) {
            b1f[n] = *(const s16x8*)&lds3[cur][1][lds_off(wc * 32 + n * 16 + lr, lg)];
            b3f[n] = *(const s16x8*)&lds3[cur][2][lds_off(wc * 32 + n * 16 + lr, lg)];
        }

        __builtin_amdgcn_s_setprio(1);
#pragma unroll
        for (int n = 0; n < 2; ++n) {
#pragma unroll
            for (int m = 0; m < 4; ++m)
                acc1[m][n] = __builtin_amdgcn_mfma_f32_16x16x32_bf16(a[m], b1f[n], acc1[m][n], 0, 0, 0);
#pragma unroll
            for (int m = 0; m < 4; ++m)
                acc3[m][n] = __builtin_amdgcn_mfma_f32_16x16x32_bf16(a[m], b3f[n], acc3[m][n], 0, 0, 0);
        }
        __builtin_amdgcn_s_setprio(0);

        __builtin_amdgcn_s_barrier();
        cur = cur + 1; if (cur == 3) cur = 0;
    }

    // epilogue: silu(acc1)*acc3 -> bf16 h
#pragma unroll
    for (int m = 0; m < 4; ++m)
#pragma unroll
        for (int n = 0; n < 2; ++n)
#pragma unroll
            for (int r = 0; r < 4; ++r) {
                int row_local = wr * 64 + m * 16 + lg * 4 + r;
                if (m0 + row_local < cnt) {
                    int col_local = wc * 32 + n * 16 + lr;
                    float g1 = acc1[m][n][r];
                    float hv = (g1 / (1.f + __expf(-g1))) * acc3[m][n][r];
                    h[(size_t)(offs + m0 + row_local) * HDIM + n0 + col_local] = f2bf(hv);
                }
            }
}

// -------- GEMM2: out[tok] += gate * (h @ w2); m97 shape: 256 thr, 128x128 --
// 4 waves (2Mx2N), wave tile 64x64, acc[4][4], MFMA:ds = 16:8 = 2.0.
// 3-buffer counted-vmcnt (4 loads/stage -> vmcnt(4)), LDS ~49 KB -> 3
// blocks/CU = 12 waves/CU; 512 active blocks fill all CUs. Exactly 2 atomic
// contributions per out element -> bitwise deterministic.
__global__ __launch_bounds__(256, 4) void gemm2_kernel(
    const unsigned short* __restrict__ h, const unsigned short* __restrict__ w2t,
    const int* __restrict__ rows_tok, const float* __restrict__ rows_gate,
    const int* __restrict__ offsets, float* __restrict__ out)
{
    int e = blockIdx.z;
    int offs = offsets[e];
    int cnt  = offsets[e + 1] - offs;
    int m0 = blockIdx.y * BM;
    if (m0 >= cnt) return;
    int n0 = blockIdx.x * BN2;   // over DIM

    __shared__ unsigned short ldsA[3][BM * BK];   // 24 KB
    __shared__ unsigned short ldsB[3][BN2 * BK];  // 24 KB
    __shared__ int   toks[BM];
    __shared__ float gts[BM];

    int tid = threadIdx.x;
    if (tid < BM) {
        int p = offs + min(m0 + tid, cnt - 1);
        toks[tid] = rows_tok[p];
        gts[tid]  = rows_gate[p];
    }
    __syncthreads();

    int lane = tid & 63;
    int wid = tid >> 6;                // 0..3
    int wr = wid >> 1, wc = wid & 1;   // 2M x 2N, wave tile 64x64
    int lr = lane & 15, lg = lane >> 4;

    // staging: 2 gload16 per matrix per buffer. Load i covers rows
    // r_i = (tid>>2) + i*64, chunk c = tid&3; g = c ^ ((r>>1)&3)
    // (identical for i=0,1 since 64-row shift preserves (r>>1)&3... (r+64)>>1
    // = r>>1 + 32, and 32 % 4 == 0).
    int srow = tid >> 2;               // 0..63
    int c4 = tid & 3;
    int g = c4 ^ ((srow >> 1) & 3);
    int arow0 = offs + min(m0 + srow, cnt - 1);
    int arow1 = offs + min(m0 + srow + 64, cnt - 1);
    const unsigned short* asrc0 = h + (size_t)arow0 * HDIM + g * 8;
    const unsigned short* asrc1 = h + (size_t)arow1 * HDIM + g * 8;
    const unsigned short* bsrc0 = w2t + ((size_t)e * DIM + n0 + srow) * HDIM + g * 8;
    const unsigned short* bsrc1 = w2t + ((size_t)e * DIM + n0 + srow + 64) * HDIM + g * 8;
    int ldsbase = wid * 512;           // shorts; +2048 for second half

    f32x4 acc[4][4] = {};

    const int NT = HDIM / BK;          // 128 K-tiles

    auto stage_t = [&](int b, int t) {
        int k0 = t * BK;
        gload16(asrc0 + k0, &ldsA[b][ldsbase]);
        gload16(asrc1 + k0, &ldsA[b][2048 + ldsbase]);
        gload16(bsrc0 + k0, &ldsB[b][ldsbase]);
        gload16(bsrc1 + k0, &ldsB[b][2048 + ldsbase]);
    };

    stage_t(0, 0);
    stage_t(1, 1);

    int cur = 0;
    for (int t = 0; t < NT; ++t) {
        if (t == NT - 1) asm volatile("s_waitcnt vmcnt(0)" ::: "memory");
        else             asm volatile("s_waitcnt vmcnt(4)" ::: "memory");
        __builtin_amdgcn_s_barrier();

        int nxt = cur + 2; if (nxt >= 3) nxt -= 3;
        if (t + 2 < NT) stage_t(nxt, t + 2);

        s16x8 a[4], bf[4];
#pragma unroll
        for (int m = 0; m < 4; ++m)
            a[m] = *(const s16x8*)&ldsA[cur][lds_off(wr * 64 + m * 16 + lr, lg)];
#pragma unroll
        for (int n = 0; n < 4; ++n)
            bf[n] = *(const s16x8*)&ldsB[cur][lds_off(wc * 64 + n * 16 + lr, lg)];

        __builtin_amdgcn_s_setprio(1);
#pragma unroll
        for (int n = 0; n < 4; ++n)
#pragma unroll
            for (int m = 0; m < 4; ++m)
                acc[m][n] = __builtin_amdgcn_mfma_f32_16x16x32_bf16(a[m], bf[n], acc[m][n], 0, 0, 0);
        __builtin_amdgcn_s_setprio(0);

        __builtin_amdgcn_s_barrier();
        cur = cur + 1; if (cur == 3) cur = 0;
    }

#pragma unroll
    for (int m = 0; m < 4; ++m)
#pragma unroll
        for (int n = 0; n < 4; ++n)
#pragma unroll
            for (int r = 0; r < 4; ++r) {
                int row_local = wr * 64 + m * 16 + lg * 4 + r;
                if (m0 + row_local < cnt) {
                    int col = n0 + wc * 64 + n * 16 + lr;
                    float v = acc[m][n][r] * gts[row_local];
                    atomicAdd(&out[(size_t)toks[row_local] * DIM + col], v);
                }
            }
}

// ---------------------------------------------------------------------------
extern "C" void kernel_launch(void* const* d_in, const int* in_sizes, int n_in,
                              void* d_out, int out_size, void* d_ws, size_t ws_size,
                              hipStream_t stream)
{
    const float* x  = (const float*)d_in[0];
    const float* wg = (const float*)d_in[1];
    const float* w1 = (const float*)d_in[2];
    const float* w3 = (const float*)d_in[3];
    const float* w2 = (const float*)d_in[4];
    float* out = (float*)d_out;

    // Workspace ~200.2 MiB. Alias: w2t<-w1t (w1t dead after gemm1).
    char* ws = (char*)d_ws;
    size_t off = 0;
    auto alloc = [&](size_t bytes) -> void* {
        void* p = ws + off;
        off = (off + bytes + 255) & ~(size_t)255;
        return p;
    };
    int*   rows_tok  = (int*)alloc((size_t)NSLOT * 4);
    float* rows_gate = (float*)alloc((size_t)NSLOT * 4);
    int*   tok_e     = (int*)alloc((size_t)NSLOT * 4);
    float* tok_w     = (float*)alloc((size_t)NSLOT * 4);
    int*   counts    = (int*)alloc(NEXP * 4);
    int*   offsets   = (int*)alloc((NEXP + 1) * 4);
    int*   cursor    = (int*)alloc(NEXP * 4);
    unsigned short* xg   = (unsigned short*)alloc((size_t)T_TOK * DIM * 2);       // 8 MiB (token order)
    unsigned short* w1t  = (unsigned short*)alloc((size_t)NEXP * HDIM * DIM * 2); // 64 MiB
    unsigned short* w3t  = (unsigned short*)alloc((size_t)NEXP * HDIM * DIM * 2); // 64 MiB
    unsigned short* hbuf = (unsigned short*)alloc((size_t)NSLOT * HDIM * 2);      // 64 MiB
    unsigned short* w2t  = w1t;   // alias: dead after gemm1

    hipMemsetAsync(counts, 0, NEXP * 4, stream);
    hipMemsetAsync(out, 0, (size_t)out_size * sizeof(float), stream);

    gate_kernel<<<T_TOK / 4, 256, 0, stream>>>(x, wg, tok_e, tok_w, counts, xg);
    scan_kernel<<<1, 64, 0, stream>>>(counts, offsets, cursor);
    assign_kernel<<<T_TOK / 256, 256, 0, stream>>>(tok_e, tok_w, offsets, cursor,
                                                   rows_tok, rows_gate);

    // w1,w3: [E][D][H] -> [E][H][D] in one dispatch
    tconv13_kernel<<<dim3(HDIM / 64, DIM / 64, 2 * NEXP), 256, 0, stream>>>(
        w1, w3, w1t, w3t);

    gemm1_kernel<<<dim3(HDIM / BN1, T_TOK / BM, NEXP), 512, 0, stream>>>(
        xg, w1t, w3t, rows_tok, offsets, hbuf);

    // w2: [E][H][D] -> [E][D][H]  (into w1t's region, now dead)
    tconv_kernel<<<dim3(DIM / 64, HDIM / 64, NEXP), 256, 0, stream>>>(w2, w2t, HDIM, DIM);

    gemm2_kernel<<<dim3(DIM / BN2, T_TOK / BM, NEXP), 256, 0, stream>>>(
        hbuf, w2t, rows_tok, rows_gate, offsets, out);
}